// Round 21
// baseline (156.438 us; speedup 1.0000x reference)
//
#include <hip/hip_runtime.h>
#include <hip/hip_bf16.h>

// x: [B=1024, N=65536] f32, index: [N] i32 permutation, group size 64.
#define BATCH   1024
#define NEUR    65536
#define NGRP    1024
#define NCHUNK  8
#define CHUNK   (NEUR / NCHUNK)       // 8192 floats per chunk (32 KB LDS)
#define CHUNK_F4 (CHUNK / 4)          // 2048 float4
#define BLK1    512                   // k1 block: 4 blocks/CU (R13-proven)
#define F4T1    (CHUNK_F4 / BLK1)     // 4 float4 per thread
#define KMAX    16                    // padded slots per (chunk, group) cell
#define SENT    CHUNK                 // sentinel LDS slot holding 0.0f
#define BLK     1024                  // build_tables / k2 / k3 block
#define ROW_F4  (NEUR / 4)            // 16384
#define R_ITERS (ROW_F4 / BLK)        // 16 (full row per k3 block — R21)
#define BUCKET_ELEMS (NCHUNK * NGRP * KMAX)   // 131072 u16 = 256 KB
#define SPILL_PER_C 120               // per-chunk spill list capacity

typedef float          f32x4 __attribute__((ext_vector_type(4)));
typedef unsigned short u16x8 __attribute__((ext_vector_type(8)));
typedef unsigned short u16x4 __attribute__((ext_vector_type(4)));

// ws: [gof u16 128 KB][bucket 256 KB][part 32 MB][spill ~4 KB][rinv 4 MB]

// Wave == one group (64 consecutive permuted positions). Ballot/popcount
// slots each member into its source-chunk cell (transposed [cell][slot]);
// the wave also writes its own cells' pad sentinels. Overflow -> per-chunk
// spill lists (k1 scans only its own chunk's ~3 entries).
__global__ void build_tables(const int* __restrict__ index,
                             unsigned short* __restrict__ gof,
                             unsigned short* __restrict__ bucket,
                             unsigned int* __restrict__ spill) {
    const int p    = blockIdx.x * blockDim.x + threadIdx.x;
    const int lane = threadIdx.x & 63;
    const int g    = p >> 6;
    const int s    = index[p];
    gof[s] = (unsigned short)g;
    const int c = s >> 13;                                 // s / CHUNK
    unsigned long long mc = 0;
    int count[NCHUNK];
    #pragma unroll
    for (int cc = 0; cc < NCHUNK; ++cc) {
        unsigned long long m = __ballot(c == cc);
        if (cc == c) mc = m;
        count[cc] = __popcll(m);
    }
    const int k = __popcll(mc & ((1ull << lane) - 1ull));
    if (k < KMAX) {
        bucket[((size_t)(c * NGRP + g)) * KMAX + k] = (unsigned short)(s & (CHUNK - 1));
    } else {
        unsigned int pos = atomicAdd(&spill[c], 1u);       // per-chunk count
        if (pos < SPILL_PER_C)
            spill[NCHUNK + c * SPILL_PER_C + pos] = ((unsigned)g << 16) | (unsigned)s;
    }
    // Pad slots kk in [count_c, KMAX): 8 cells x 16 slots = 128 = 2 lane-passes.
    #pragma unroll
    for (int j = 0; j < 2; ++j) {
        const int slot = lane + j * 64;                    // 0..127
        const int cc = slot >> 4, kk = slot & 15;
        if (kk >= count[cc])
            bucket[((size_t)(cc * NGRP + g)) * KMAX + kk] = (unsigned short)SENT;
    }
}

// k1: one block per (row, chunk). R14-proven body: global_load_lds width=16
// staging (wave-uniform base + lane*16), bucket u16x8 loads + spill count
// hoisted above the barrier, 16 branch-free sentinel-padded gather-adds per
// owned group (t, t+512), coalesced plain partial stores.
__global__ __launch_bounds__(BLK1, 8)
void k1_partial(const float* __restrict__ x,
                const unsigned short* __restrict__ bucket,
                const unsigned int* __restrict__ spill,
                float* __restrict__ part) {
    __shared__ float xs[CHUNK + 16];   // 32 KB chunk + sentinel
    const int bc = blockIdx.x;
    const int b  = bc >> 3;            // row
    const int c  = bc & 7;             // chunk
    const int t  = threadIdx.x;

    // Hoisted independent L2 loads: in flight during staging.
    const unsigned short* __restrict__ bk0 =
        bucket + ((size_t)(c * NGRP + t)) * KMAX;          // 32 B contiguous
    const unsigned short* __restrict__ bk1 =
        bucket + ((size_t)(c * NGRP + t + 512)) * KMAX;
    const u16x8 w0 = *(const u16x8*)(bk0);
    const u16x8 w1 = *(const u16x8*)(bk0 + 8);
    const u16x8 w2 = *(const u16x8*)(bk1);
    const u16x8 w3 = *(const u16x8*)(bk1 + 8);
    const unsigned int ns = spill[c];  // my chunk's spill count (~0-5)

    if (t == 0) xs[SENT] = 0.0f;

    // Async global->LDS staging, width=16.
    const float4* __restrict__ src =
        (const float4*)(x + (size_t)b * NEUR + (size_t)c * CHUNK);
    float4* xs4 = (float4*)xs;
    #pragma unroll
    for (int i = 0; i < F4T1; ++i) {
        __builtin_amdgcn_global_load_lds(
            (const __attribute__((address_space(1))) unsigned int*)(src + i * BLK1 + t),
            (__attribute__((address_space(3))) unsigned int*)(xs4 + i * BLK1 + t),
            16, 0, 0);
    }
    __syncthreads();                   // drains vmcnt (DMA) + lgkmcnt (sentinel)

    float a0 = 0.0f, a1 = 0.0f, b0 = 0.0f, b1 = 0.0f;
    #pragma unroll
    for (int j = 0; j < 8; ++j) {
        a0 += xs[w0[j]];
        a1 += xs[w1[j]];
        b0 += xs[w2[j]];
        b1 += xs[w3[j]];               // pads hit the 0.0 sentinel
    }

    // My chunk's spill entries only (~3): short scan from L2.
    const unsigned int* __restrict__ sl = spill + NCHUNK + c * SPILL_PER_C;
    for (unsigned int e = 0; e < ns; ++e) {
        const unsigned int ent = sl[e];
        const float v = xs[ent & 0x1FFFu];
        const int gg = (int)(ent >> 16);
        if (gg == t)            a1 += v;
        else if (gg == t + 512) b1 += v;
    }

    float* __restrict__ prow = part + ((size_t)b * NCHUNK + c) * NGRP;
    prow[t]       = a0 + a1;           // coalesced
    prow[t + 512] = b0 + b1;
}

// k2: collapse part[b][c][g] -> rinv[b][g] = 1/sum_c once (R19-proven: took
// 57 MB of prologue traffic off k3). Same c-order -> bit-identical output.
__global__ __launch_bounds__(BLK, 8)
void k2_reduce(const float* __restrict__ part,
               float* __restrict__ rinv) {
    const int b = blockIdx.x;
    const int t = threadIdx.x;
    const float* __restrict__ prow = part + (size_t)b * NCHUNK * NGRP;
    float s = 0.0f;
    #pragma unroll
    for (int c = 0; c < NCHUNK; ++c) s += prow[c * NGRP + t];  // coalesced
    rinv[(size_t)b * NGRP + t] = 1.0f / s;                     // coalesced
}

// k3: one block per FULL row (R21: 1024 blocks x 1024 thr — halves the
// prologue count vs half-row and doubles each block's uninterrupted
// load/store pipeline; same 2 blocks/CU). 1024-thr proven in R14/R19/R20
// (512-thr regressed). Reverse order so L3-hottest rows go first. NT stores
// keep the 256 MB out-stream from evicting x (R10 win / R17 regression).
__global__ __launch_bounds__(BLK, 8)
void k3_scale(const float* __restrict__ x,
              const unsigned short* __restrict__ gof,
              const float* __restrict__ rinv,
              float* __restrict__ out) {
    __shared__ float rsum[NGRP];       // 4 KB only
    const int b = (BATCH - 1) - blockIdx.x;
    const int t = threadIdx.x;

    rsum[t] = rinv[(size_t)b * NGRP + t];   // one coalesced 4 KB load
    __syncthreads();

    const float4* __restrict__ xrow4 = (const float4*)(x + (size_t)b * NEUR);
    const u16x4*  __restrict__ gof4  = (const u16x4*)gof;  // 8 B per float4
    f32x4*        __restrict__ orow4 = (f32x4*)(out + (size_t)b * NEUR);

    #pragma unroll
    for (int it = 0; it < R_ITERS; ++it) {
        const int e = it * BLK + t;
        const float4 v = xrow4[e];     // L3-hot re-read
        const u16x4 g = gof4[e];       // 128 KB table, L2-resident
        f32x4 o;
        o.x = v.x * rsum[g.x];
        o.y = v.y * rsum[g.y];
        o.z = v.z * rsum[g.z];
        o.w = v.w * rsum[g.w];
        __builtin_nontemporal_store(o, &orow4[e]);  // don't evict x from L3
    }
}

extern "C" void kernel_launch(void* const* d_in, const int* in_sizes, int n_in,
                              void* d_out, int out_size, void* d_ws, size_t ws_size,
                              hipStream_t stream) {
    const float* x     = (const float*)d_in[0];
    const int*   index = (const int*)d_in[1];
    float*       out   = (float*)d_out;

    unsigned short* gof    = (unsigned short*)d_ws;                 // 128 KB
    unsigned short* bucket = gof + NEUR;                            // 256 KB
    float*          part   = (float*)(bucket + BUCKET_ELEMS);       // 32 MB
    unsigned int*   spill  = (unsigned int*)(part + (size_t)BATCH * NCHUNK * NGRP);
    float*          rinv   = (float*)(spill + NCHUNK * (1 + SPILL_PER_C) + 8);

    hipMemsetAsync(spill, 0, NCHUNK * sizeof(unsigned int), stream);
    build_tables<<<NEUR / BLK, BLK, 0, stream>>>(index, gof, bucket, spill);
    k1_partial<<<BATCH * NCHUNK, BLK1, 0, stream>>>(x, bucket, spill, part);
    k2_reduce<<<BATCH, BLK, 0, stream>>>(part, rinv);
    k3_scale<<<BATCH, BLK, 0, stream>>>(x, gof, rinv, out);
}

// Round 22
// 146.554 us; speedup vs baseline: 1.0674x; 1.0674x over previous
//
#include <hip/hip_runtime.h>
#include <hip/hip_bf16.h>

// x: [B=1024, N=65536] f32, index: [N] i32 permutation, group size 64.
// FINAL CONFIG == R19 (session best, 145.0 us):
//   build_tables -> k1 (row,chunk 512thr) -> k2 (reduce) -> k3 (half-row 1024thr, NT)
#define BATCH   1024
#define NEUR    65536
#define NGRP    1024
#define NCHUNK  8
#define CHUNK   (NEUR / NCHUNK)       // 8192 floats per chunk (32 KB LDS)
#define CHUNK_F4 (CHUNK / 4)          // 2048 float4
#define BLK1    512                   // k1 block: 4 blocks/CU (R13-proven)
#define F4T1    (CHUNK_F4 / BLK1)     // 4 float4 per thread
#define KMAX    16                    // padded slots per (chunk, group) cell
#define SENT    CHUNK                 // sentinel LDS slot holding 0.0f
#define BLK     1024                  // build_tables / k2 / k3 block
#define ROW_F4  (NEUR / 4)            // 16384
#define HALF_F4 (ROW_F4 / 2)          // 8192
#define H_ITERS (HALF_F4 / BLK)       // 8
#define BUCKET_ELEMS (NCHUNK * NGRP * KMAX)   // 131072 u16 = 256 KB
#define SPILL_PER_C 120               // per-chunk spill list capacity

typedef float          f32x4 __attribute__((ext_vector_type(4)));
typedef unsigned short u16x8 __attribute__((ext_vector_type(8)));
typedef unsigned short u16x4 __attribute__((ext_vector_type(4)));

// ws: [gof u16 128 KB][bucket 256 KB][part 32 MB][spill ~4 KB][rinv 4 MB]

// Wave == one group (64 consecutive permuted positions). Ballot/popcount
// slots each member into its source-chunk cell (transposed [cell][slot]);
// the wave also writes its own cells' pad sentinels. Overflow -> per-chunk
// spill lists (k1 scans only its own chunk's ~3 entries).
__global__ void build_tables(const int* __restrict__ index,
                             unsigned short* __restrict__ gof,
                             unsigned short* __restrict__ bucket,
                             unsigned int* __restrict__ spill) {
    const int p    = blockIdx.x * blockDim.x + threadIdx.x;
    const int lane = threadIdx.x & 63;
    const int g    = p >> 6;
    const int s    = index[p];
    gof[s] = (unsigned short)g;
    const int c = s >> 13;                                 // s / CHUNK
    unsigned long long mc = 0;
    int count[NCHUNK];
    #pragma unroll
    for (int cc = 0; cc < NCHUNK; ++cc) {
        unsigned long long m = __ballot(c == cc);
        if (cc == c) mc = m;
        count[cc] = __popcll(m);
    }
    const int k = __popcll(mc & ((1ull << lane) - 1ull));
    if (k < KMAX) {
        bucket[((size_t)(c * NGRP + g)) * KMAX + k] = (unsigned short)(s & (CHUNK - 1));
    } else {
        unsigned int pos = atomicAdd(&spill[c], 1u);       // per-chunk count
        if (pos < SPILL_PER_C)
            spill[NCHUNK + c * SPILL_PER_C + pos] = ((unsigned)g << 16) | (unsigned)s;
    }
    // Pad slots kk in [count_c, KMAX): 8 cells x 16 slots = 128 = 2 lane-passes.
    #pragma unroll
    for (int j = 0; j < 2; ++j) {
        const int slot = lane + j * 64;                    // 0..127
        const int cc = slot >> 4, kk = slot & 15;
        if (kk >= count[cc])
            bucket[((size_t)(cc * NGRP + g)) * KMAX + kk] = (unsigned short)SENT;
    }
}

// k1: one block per (row, chunk). R14-proven body: global_load_lds width=16
// staging (wave-uniform base + lane*16), bucket u16x8 loads + spill count
// hoisted above the barrier, 16 branch-free sentinel-padded gather-adds per
// owned group (t, t+512), coalesced plain partial stores.
__global__ __launch_bounds__(BLK1, 8)
void k1_partial(const float* __restrict__ x,
                const unsigned short* __restrict__ bucket,
                const unsigned int* __restrict__ spill,
                float* __restrict__ part) {
    __shared__ float xs[CHUNK + 16];   // 32 KB chunk + sentinel
    const int bc = blockIdx.x;
    const int b  = bc >> 3;            // row
    const int c  = bc & 7;             // chunk
    const int t  = threadIdx.x;

    // Hoisted independent L2 loads: in flight during staging.
    const unsigned short* __restrict__ bk0 =
        bucket + ((size_t)(c * NGRP + t)) * KMAX;          // 32 B contiguous
    const unsigned short* __restrict__ bk1 =
        bucket + ((size_t)(c * NGRP + t + 512)) * KMAX;
    const u16x8 w0 = *(const u16x8*)(bk0);
    const u16x8 w1 = *(const u16x8*)(bk0 + 8);
    const u16x8 w2 = *(const u16x8*)(bk1);
    const u16x8 w3 = *(const u16x8*)(bk1 + 8);
    const unsigned int ns = spill[c];  // my chunk's spill count (~0-5)

    if (t == 0) xs[SENT] = 0.0f;

    // Async global->LDS staging, width=16.
    const float4* __restrict__ src =
        (const float4*)(x + (size_t)b * NEUR + (size_t)c * CHUNK);
    float4* xs4 = (float4*)xs;
    #pragma unroll
    for (int i = 0; i < F4T1; ++i) {
        __builtin_amdgcn_global_load_lds(
            (const __attribute__((address_space(1))) unsigned int*)(src + i * BLK1 + t),
            (__attribute__((address_space(3))) unsigned int*)(xs4 + i * BLK1 + t),
            16, 0, 0);
    }
    __syncthreads();                   // drains vmcnt (DMA) + lgkmcnt (sentinel)

    float a0 = 0.0f, a1 = 0.0f, b0 = 0.0f, b1 = 0.0f;
    #pragma unroll
    for (int j = 0; j < 8; ++j) {
        a0 += xs[w0[j]];
        a1 += xs[w1[j]];
        b0 += xs[w2[j]];
        b1 += xs[w3[j]];               // pads hit the 0.0 sentinel
    }

    // My chunk's spill entries only (~3): short scan from L2.
    const unsigned int* __restrict__ sl = spill + NCHUNK + c * SPILL_PER_C;
    for (unsigned int e = 0; e < ns; ++e) {
        const unsigned int ent = sl[e];
        const float v = xs[ent & 0x1FFFu];
        const int gg = (int)(ent >> 16);
        if (gg == t)            a1 += v;
        else if (gg == t + 512) b1 += v;
    }

    float* __restrict__ prow = part + ((size_t)b * NCHUNK + c) * NGRP;
    prow[t]       = a0 + a1;           // coalesced
    prow[t + 512] = b0 + b1;
}

// k2: collapse part[b][c][g] -> rinv[b][g] = 1/sum_c once (R19-proven: took
// 57 MB of prologue traffic off k3). Same c-order -> bit-identical output.
__global__ __launch_bounds__(BLK, 8)
void k2_reduce(const float* __restrict__ part,
               float* __restrict__ rinv) {
    const int b = blockIdx.x;
    const int t = threadIdx.x;
    const float* __restrict__ prow = part + (size_t)b * NCHUNK * NGRP;
    float s = 0.0f;
    #pragma unroll
    for (int c = 0; c < NCHUNK; ++c) s += prow[c * NGRP + t];  // coalesced
    rinv[(size_t)b * NGRP + t] = 1.0f / s;                     // coalesced
}

// k3: one block per HALF-row, 1024 threads — the measured optimum of the
// granularity curve (quarter-row R11 / half-512 R20 / full-row R21 all
// regressed). Reverse order so the L3-hottest rows go first. Single 4 KB
// rinv load, coalesced scale, NONTEMPORAL store (protects x's L3 residency:
// R10 added = win, R17 removed = regression).
__global__ __launch_bounds__(BLK, 8)
void k3_scale(const float* __restrict__ x,
              const unsigned short* __restrict__ gof,
              const float* __restrict__ rinv,
              float* __restrict__ out) {
    __shared__ float rsum[NGRP];       // 4 KB only
    const int rb   = blockIdx.x;
    const int b    = (BATCH - 1) - (rb >> 1);
    const int half = rb & 1;
    const int t    = threadIdx.x;

    rsum[t] = rinv[(size_t)b * NGRP + t];   // one coalesced 4 KB load
    __syncthreads();

    const float4* __restrict__ xrow4 = (const float4*)(x + (size_t)b * NEUR);
    const u16x4*  __restrict__ gof4  = (const u16x4*)gof;  // 8 B per float4
    f32x4*        __restrict__ orow4 = (f32x4*)(out + (size_t)b * NEUR);

    #pragma unroll
    for (int it = 0; it < H_ITERS; ++it) {
        const int e = half * HALF_F4 + it * BLK + t;
        const float4 v = xrow4[e];     // L3-hot re-read
        const u16x4 g = gof4[e];       // 128 KB table, L2-resident
        f32x4 o;
        o.x = v.x * rsum[g.x];
        o.y = v.y * rsum[g.y];
        o.z = v.z * rsum[g.z];
        o.w = v.w * rsum[g.w];
        __builtin_nontemporal_store(o, &orow4[e]);  // don't evict x from L3
    }
}

extern "C" void kernel_launch(void* const* d_in, const int* in_sizes, int n_in,
                              void* d_out, int out_size, void* d_ws, size_t ws_size,
                              hipStream_t stream) {
    const float* x     = (const float*)d_in[0];
    const int*   index = (const int*)d_in[1];
    float*       out   = (float*)d_out;

    unsigned short* gof    = (unsigned short*)d_ws;                 // 128 KB
    unsigned short* bucket = gof + NEUR;                            // 256 KB
    float*          part   = (float*)(bucket + BUCKET_ELEMS);       // 32 MB
    unsigned int*   spill  = (unsigned int*)(part + (size_t)BATCH * NCHUNK * NGRP);
    float*          rinv   = (float*)(spill + NCHUNK * (1 + SPILL_PER_C) + 8);

    hipMemsetAsync(spill, 0, NCHUNK * sizeof(unsigned int), stream);
    build_tables<<<NEUR / BLK, BLK, 0, stream>>>(index, gof, bucket, spill);
    k1_partial<<<BATCH * NCHUNK, BLK1, 0, stream>>>(x, bucket, spill, part);
    k2_reduce<<<BATCH, BLK, 0, stream>>>(part, rinv);
    k3_scale<<<BATCH * 2, BLK, 0, stream>>>(x, gof, rinv, out);
}

// Round 23
// 144.434 us; speedup vs baseline: 1.0831x; 1.0147x over previous
//
#include <hip/hip_runtime.h>
#include <hip/hip_bf16.h>

// x: [B=1024, N=65536] f32, index: [N] i32 permutation, group size 64.
// Structure == R19 (session best). R23 single variable: part kept OUT of L3
// (NT store in k1, NT load in k2) so x's L3 residency survives to k3's re-read.
#define BATCH   1024
#define NEUR    65536
#define NGRP    1024
#define NCHUNK  8
#define CHUNK   (NEUR / NCHUNK)       // 8192 floats per chunk (32 KB LDS)
#define CHUNK_F4 (CHUNK / 4)          // 2048 float4
#define BLK1    512                   // k1 block: 4 blocks/CU (R13-proven)
#define F4T1    (CHUNK_F4 / BLK1)     // 4 float4 per thread
#define KMAX    16                    // padded slots per (chunk, group) cell
#define SENT    CHUNK                 // sentinel LDS slot holding 0.0f
#define BLK     1024                  // build_tables / k2 / k3 block
#define ROW_F4  (NEUR / 4)            // 16384
#define HALF_F4 (ROW_F4 / 2)          // 8192
#define H_ITERS (HALF_F4 / BLK)       // 8
#define BUCKET_ELEMS (NCHUNK * NGRP * KMAX)   // 131072 u16 = 256 KB
#define SPILL_PER_C 120               // per-chunk spill list capacity

typedef float          f32x4 __attribute__((ext_vector_type(4)));
typedef unsigned short u16x8 __attribute__((ext_vector_type(8)));
typedef unsigned short u16x4 __attribute__((ext_vector_type(4)));

// ws: [gof u16 128 KB][bucket 256 KB][part 32 MB][spill ~4 KB][rinv 4 MB]

// Wave == one group (64 consecutive permuted positions). Ballot/popcount
// slots each member into its source-chunk cell (transposed [cell][slot]);
// the wave also writes its own cells' pad sentinels. Overflow -> per-chunk
// spill lists (k1 scans only its own chunk's ~3 entries).
__global__ void build_tables(const int* __restrict__ index,
                             unsigned short* __restrict__ gof,
                             unsigned short* __restrict__ bucket,
                             unsigned int* __restrict__ spill) {
    const int p    = blockIdx.x * blockDim.x + threadIdx.x;
    const int lane = threadIdx.x & 63;
    const int g    = p >> 6;
    const int s    = index[p];
    gof[s] = (unsigned short)g;
    const int c = s >> 13;                                 // s / CHUNK
    unsigned long long mc = 0;
    int count[NCHUNK];
    #pragma unroll
    for (int cc = 0; cc < NCHUNK; ++cc) {
        unsigned long long m = __ballot(c == cc);
        if (cc == c) mc = m;
        count[cc] = __popcll(m);
    }
    const int k = __popcll(mc & ((1ull << lane) - 1ull));
    if (k < KMAX) {
        bucket[((size_t)(c * NGRP + g)) * KMAX + k] = (unsigned short)(s & (CHUNK - 1));
    } else {
        unsigned int pos = atomicAdd(&spill[c], 1u);       // per-chunk count
        if (pos < SPILL_PER_C)
            spill[NCHUNK + c * SPILL_PER_C + pos] = ((unsigned)g << 16) | (unsigned)s;
    }
    // Pad slots kk in [count_c, KMAX): 8 cells x 16 slots = 128 = 2 lane-passes.
    #pragma unroll
    for (int j = 0; j < 2; ++j) {
        const int slot = lane + j * 64;                    // 0..127
        const int cc = slot >> 4, kk = slot & 15;
        if (kk >= count[cc])
            bucket[((size_t)(cc * NGRP + g)) * KMAX + kk] = (unsigned short)SENT;
    }
}

// k1: one block per (row, chunk). R14-proven body: global_load_lds width=16
// staging, bucket u16x8 loads + spill count hoisted above the barrier,
// 16 branch-free sentinel-padded gather-adds per owned group. R23: partial
// stores are NONTEMPORAL — part is write-once/read-once, keep it out of L3
// so x's residency survives to k3's re-read.
__global__ __launch_bounds__(BLK1, 8)
void k1_partial(const float* __restrict__ x,
                const unsigned short* __restrict__ bucket,
                const unsigned int* __restrict__ spill,
                float* __restrict__ part) {
    __shared__ float xs[CHUNK + 16];   // 32 KB chunk + sentinel
    const int bc = blockIdx.x;
    const int b  = bc >> 3;            // row
    const int c  = bc & 7;             // chunk
    const int t  = threadIdx.x;

    // Hoisted independent L2 loads: in flight during staging.
    const unsigned short* __restrict__ bk0 =
        bucket + ((size_t)(c * NGRP + t)) * KMAX;          // 32 B contiguous
    const unsigned short* __restrict__ bk1 =
        bucket + ((size_t)(c * NGRP + t + 512)) * KMAX;
    const u16x8 w0 = *(const u16x8*)(bk0);
    const u16x8 w1 = *(const u16x8*)(bk0 + 8);
    const u16x8 w2 = *(const u16x8*)(bk1);
    const u16x8 w3 = *(const u16x8*)(bk1 + 8);
    const unsigned int ns = spill[c];  // my chunk's spill count (~0-5)

    if (t == 0) xs[SENT] = 0.0f;

    // Async global->LDS staging, width=16.
    const float4* __restrict__ src =
        (const float4*)(x + (size_t)b * NEUR + (size_t)c * CHUNK);
    float4* xs4 = (float4*)xs;
    #pragma unroll
    for (int i = 0; i < F4T1; ++i) {
        __builtin_amdgcn_global_load_lds(
            (const __attribute__((address_space(1))) unsigned int*)(src + i * BLK1 + t),
            (__attribute__((address_space(3))) unsigned int*)(xs4 + i * BLK1 + t),
            16, 0, 0);
    }
    __syncthreads();                   // drains vmcnt (DMA) + lgkmcnt (sentinel)

    float a0 = 0.0f, a1 = 0.0f, b0 = 0.0f, b1 = 0.0f;
    #pragma unroll
    for (int j = 0; j < 8; ++j) {
        a0 += xs[w0[j]];
        a1 += xs[w1[j]];
        b0 += xs[w2[j]];
        b1 += xs[w3[j]];               // pads hit the 0.0 sentinel
    }

    // My chunk's spill entries only (~3): short scan from L2.
    const unsigned int* __restrict__ sl = spill + NCHUNK + c * SPILL_PER_C;
    for (unsigned int e = 0; e < ns; ++e) {
        const unsigned int ent = sl[e];
        const float v = xs[ent & 0x1FFFu];
        const int gg = (int)(ent >> 16);
        if (gg == t)            a1 += v;
        else if (gg == t + 512) b1 += v;
    }

    float* __restrict__ prow = part + ((size_t)b * NCHUNK + c) * NGRP;
    __builtin_nontemporal_store(a0 + a1, &prow[t]);        // NT: don't pollute L3
    __builtin_nontemporal_store(b0 + b1, &prow[t + 512]);
}

// k2: collapse part[b][c][g] -> rinv[b][g] = 1/sum_c (R19-proven). R23: part
// reads are NONTEMPORAL LOADS (part is dead after this — don't allocate 32 MB
// in L3 between k1's staging and k3's re-read). Same c-order -> bit-identical.
__global__ __launch_bounds__(BLK, 8)
void k2_reduce(const float* __restrict__ part,
               float* __restrict__ rinv) {
    const int b = blockIdx.x;
    const int t = threadIdx.x;
    const float* __restrict__ prow = part + (size_t)b * NCHUNK * NGRP;
    float s = 0.0f;
    #pragma unroll
    for (int c = 0; c < NCHUNK; ++c)
        s += __builtin_nontemporal_load(prow + c * NGRP + t);  // coalesced, NT
    rinv[(size_t)b * NGRP + t] = 1.0f / s;                     // plain (k3 wants it)
}

// k3: one block per HALF-row, 1024 threads — measured optimum (quarter/R11,
// half-512/R20, full/R21 all regressed). Reverse order so L3-hottest rows go
// first. Single 4 KB rinv load, coalesced scale, NONTEMPORAL out store
// (protects x's L3 residency: R10 added = win, R17 removed = regression).
__global__ __launch_bounds__(BLK, 8)
void k3_scale(const float* __restrict__ x,
              const unsigned short* __restrict__ gof,
              const float* __restrict__ rinv,
              float* __restrict__ out) {
    __shared__ float rsum[NGRP];       // 4 KB only
    const int rb   = blockIdx.x;
    const int b    = (BATCH - 1) - (rb >> 1);
    const int half = rb & 1;
    const int t    = threadIdx.x;

    rsum[t] = rinv[(size_t)b * NGRP + t];   // one coalesced 4 KB load
    __syncthreads();

    const float4* __restrict__ xrow4 = (const float4*)(x + (size_t)b * NEUR);
    const u16x4*  __restrict__ gof4  = (const u16x4*)gof;  // 8 B per float4
    f32x4*        __restrict__ orow4 = (f32x4*)(out + (size_t)b * NEUR);

    #pragma unroll
    for (int it = 0; it < H_ITERS; ++it) {
        const int e = half * HALF_F4 + it * BLK + t;
        const float4 v = xrow4[e];     // L3-hot re-read
        const u16x4 g = gof4[e];       // 128 KB table, L2-resident
        f32x4 o;
        o.x = v.x * rsum[g.x];
        o.y = v.y * rsum[g.y];
        o.z = v.z * rsum[g.z];
        o.w = v.w * rsum[g.w];
        __builtin_nontemporal_store(o, &orow4[e]);  // don't evict x from L3
    }
}

extern "C" void kernel_launch(void* const* d_in, const int* in_sizes, int n_in,
                              void* d_out, int out_size, void* d_ws, size_t ws_size,
                              hipStream_t stream) {
    const float* x     = (const float*)d_in[0];
    const int*   index = (const int*)d_in[1];
    float*       out   = (float*)d_out;

    unsigned short* gof    = (unsigned short*)d_ws;                 // 128 KB
    unsigned short* bucket = gof + NEUR;                            // 256 KB
    float*          part   = (float*)(bucket + BUCKET_ELEMS);       // 32 MB
    unsigned int*   spill  = (unsigned int*)(part + (size_t)BATCH * NCHUNK * NGRP);
    float*          rinv   = (float*)(spill + NCHUNK * (1 + SPILL_PER_C) + 8);

    hipMemsetAsync(spill, 0, NCHUNK * sizeof(unsigned int), stream);
    build_tables<<<NEUR / BLK, BLK, 0, stream>>>(index, gof, bucket, spill);
    k1_partial<<<BATCH * NCHUNK, BLK1, 0, stream>>>(x, bucket, spill, part);
    k2_reduce<<<BATCH, BLK, 0, stream>>>(part, rinv);
    k3_scale<<<BATCH * 2, BLK, 0, stream>>>(x, gof, rinv, out);
}